// Round 9
// baseline (6304.975 us; speedup 1.0000x reference)
//
#include <hip/hip_runtime.h>
#include <math.h>

// ---------------- dims ----------------
#define B_ 32
#define C_ 3
#define HW_ 224
#define NP_ 14
#define PS_ 16
#define S_ 197        // NP*NP + 1
#define SP_ 224       // S padded to multiple of 32 (K dim of AV)
#define D_ 768
#define NH_ 12
#define DH_ 64
#define L_ 12
#define MLP_ 3072
#define OUT_ 1000

#define MTOK_ (B_ * S_)               // 6304

// blocked (K-octet-major) layouts: buf[k/8][rows][8] -> adjacent rows are
// adjacent 16B chunks; a wave's MFMA fragment load is 4x256B segments.
#define OID(rows, r, k) ((((long long)((k) >> 3)) * (rows) + (r)) * 8 + ((k) & 7))

#define NBS_ (B_ * NH_ * S_)          // 75648 rows of att
#define VROWS_ (NH_ * B_ * DH_)       // 24576 rows of vt

typedef unsigned short u16;
typedef unsigned int u32;
typedef __attribute__((ext_vector_type(8))) _Float16 half8_t;
typedef __attribute__((ext_vector_type(4))) float f32x4;

// ---------------- fp16 helpers ----------------
__device__ __forceinline__ u16 f2h(float x) {
    union { _Float16 h; u16 u; } c; c.h = (_Float16)x; return c.u;
}
__device__ __forceinline__ float h2f(u16 u) {
    union { _Float16 h; u16 u; } c; c.u = u; return (float)c.h;
}

// ================= fp16 MFMA GEMM (register-direct fragments, no LDS, no barriers) =================
// C = A @ B^T(stored blocked [K/8][rowsN][8]), fp16 inputs, fp32 accumulate.
// Each of 4 waves owns a 64x64 quadrant of the 128x128 tile and loads its own
// MFMA fragments straight from global to VGPRs (global_load_dwordx4, 4x256B
// segments per instruction), 3-deep register-rotated pipeline (a0/a1/a2).
// No __shared__, no s_barrier: waves free-run; compiler inserts counted vmcnt.
// Per-z offsets: off = (z/div)*so + (z%div)*si (element offsets into blocked bufs).
// ksplit>1: blockIdx.z = K chunk; epilogue atomicAdd into C; bias only chunk 0.
// mode 0: C[row*ldc+col] = acc+bias (+C_old if accum); remap row=grow+grow/196+1
// mode 1: gelu(acc+bias) -> fp16 at OID(orows, grow, col)
// mode 2: (acc+bias)     -> fp16 at OID(orows, grow, col); zero-fills cols [N,ldc)
// mode 4: fused QKV epilogue (z = head):
//   col<128 -> Oq [z*MTOK_*128 + OID(MTOK_, grow, col)]          (q|k features)
//   col>=128-> Oq2[z*B_*DH_*8 + OID(VROWS_, n*DH_+(col-128), s)] (v transposed)
__global__ __launch_bounds__(256) void mfma_gemm_kernel(
    const u16* __restrict__ Aq, const u16* __restrict__ Bq,
    const float* __restrict__ bias, float* __restrict__ C,
    u16* __restrict__ Oq, u16* __restrict__ Oq2,
    int M, int N, int K, int mplaneA, int mplaneB, int ldc, long long orows,
    int mode, int accum, int remap, int ksplit,
    int divA, long long sAo, long long sAi,
    int divB, long long sBo, long long sBi,
    int divC, long long sCo, long long sCi,
    int divBias, long long sBiaso, long long sBiasi)
{
    int z = blockIdx.z;
    int kz = 0;
    if (ksplit > 1) { kz = z; z = 0; }
    long long aoff = (long long)(z / divA) * sAo + (long long)(z % divA) * sAi;
    long long boff = (long long)(z / divB) * sBo + (long long)(z % divB) * sBi;
    long long coff = (long long)(z / divC) * sCo + (long long)(z % divC) * sCi;
    long long biasoff = (long long)(z / divBias) * sBiaso + (long long)(z % divBias) * sBiasi;

    // ---- bijective XCD-chunked swizzle of the 2D grid (m204) ----
    int nwgx = gridDim.x;
    int nwg = nwgx * gridDim.y;
    int bid = blockIdx.y * nwgx + blockIdx.x;
    int xcd = bid & 7, lid = bid >> 3;
    int qq = nwg >> 3, rr8 = nwg & 7;
    int sw = ((xcd < rr8) ? xcd * (qq + 1) : rr8 * (qq + 1) + (xcd - rr8) * qq) + lid;
    int bx = sw % nwgx, by = sw / nwgx;

    int tid = threadIdx.x;
    int lane = tid & 63;
    int w = tid >> 6;                  // wave id 0..3
    int wm = (w >> 1) * 64, wn = (w & 1) * 64;
    int m0 = by * 128, n0 = bx * 128;
    int lm = lane & 15, qd = lane >> 4;

    int kc = K / ksplit;
    int kbeg = kz * kc;
    int nsteps = kc / 32;

    // per-lane fragment base pointers (rows clamped; at plane kbeg/8 + qd)
    const u16* ap[4];
    const u16* bp[4];
#pragma unroll
    for (int i = 0; i < 4; ++i) {
        int ar = m0 + wm + i * 16 + lm; if (ar > M - 1) ar = M - 1;
        int br = n0 + wn + i * 16 + lm; if (br > N - 1) br = N - 1;
        ap[i] = Aq + aoff + ((long long)((kbeg >> 3) + qd) * mplaneA + ar) * 8;
        bp[i] = Bq + boff + ((long long)((kbeg >> 3) + qd) * mplaneB + br) * 8;
    }
    const long long astep = 4LL * mplaneA * 8;   // elements per 32-K step
    const long long bstep = 4LL * mplaneB * 8;

    f32x4 acc[4][4];
#pragma unroll
    for (int i = 0; i < 4; ++i)
#pragma unroll
        for (int j = 0; j < 4; ++j)
            acc[i][j] = (f32x4){0.f, 0.f, 0.f, 0.f};

    half8_t a0[4], b0[4], a1[4], b1[4], a2[4], b2[4];
    auto LD = [&](half8_t* A8, half8_t* B8, int t) {
        long long ao = (long long)t * astep, bo = (long long)t * bstep;
#pragma unroll
        for (int i = 0; i < 4; ++i) {
            A8[i] = *(const half8_t*)(ap[i] + ao);
            B8[i] = *(const half8_t*)(bp[i] + bo);
        }
    };
    auto MM = [&](half8_t* A8, half8_t* B8) {
#pragma unroll
        for (int i = 0; i < 4; ++i)
#pragma unroll
            for (int j = 0; j < 4; ++j)
                acc[i][j] = __builtin_amdgcn_mfma_f32_16x16x32_f16(A8[i], B8[j], acc[i][j], 0, 0, 0);
    };

    // 3-deep register-rotated pipeline (static names, no runtime indexing)
    if (nsteps > 0) LD(a0, b0, 0);
    if (nsteps > 1) LD(a1, b1, 1);
    int t = 0;
    for (; t + 3 <= nsteps; t += 3) {
        LD(a2, b2, t + 2);
        MM(a0, b0);
        if (t + 3 < nsteps) LD(a0, b0, t + 3);
        MM(a1, b1);
        if (t + 4 < nsteps) LD(a1, b1, t + 4);
        MM(a2, b2);
    }
    if (t < nsteps)     MM(a0, b0);
    if (t + 1 < nsteps) MM(a1, b1);

    float* Cb = C ? C + coff : nullptr;
    u16* Ob = Oq ? Oq + coff : nullptr;
    const float* biasb = (bias && kz == 0) ? bias + biasoff : nullptr;

    // ---- epilogue: C/D layout col=lane&15, row=quad*4+reg ----
#pragma unroll
    for (int j = 0; j < 4; ++j) {
        int col = n0 + wn + j * 16 + lm;
        bool cok = col < N;
        float bv = (cok && biasb) ? biasb[col] : 0.f;
#pragma unroll
        for (int i = 0; i < 4; ++i) {
#pragma unroll
            for (int r = 0; r < 4; ++r) {
                int grow = m0 + wm + i * 16 + qd * 4 + r;
                if (grow >= M) continue;
                float v = acc[i][j][r] + bv;
                if (mode == 2) {
                    if (col >= ldc) continue;          // never cross plane range
                    if (!cok) v = 0.f;                 // zero-fill K padding
                    Ob[OID(orows, grow, col)] = f2h(v);
                } else if (mode == 4) {
                    if (!cok) continue;                // col < 192
                    if (col < 128) {
                        Oq[(long long)z * (MTOK_ * 128LL) + OID(MTOK_, grow, col)] = f2h(v);
                    } else {
                        int nn = grow / S_;
                        int ss = grow - nn * S_;
                        Oq2[(long long)z * (B_ * DH_ * 8LL) + OID(VROWS_, nn * DH_ + (col - 128), ss)] = f2h(v);
                    }
                } else if (mode == 1) {
                    if (!cok) continue;
                    v = 0.5f * v * (1.0f + erff(v * 0.70710678118654752f));
                    Ob[OID(orows, grow, col)] = f2h(v);
                } else {
                    if (!cok) continue;
                    int orow = remap ? (grow + grow / 196 + 1) : grow;
                    long long idx = (long long)orow * ldc + col;
                    if (ksplit > 1) {
                        atomicAdd(&Cb[idx], v);        // accum semantics, nondet order
                    } else {
                        if (accum) v += Cb[idx];
                        Cb[idx] = v;
                    }
                }
            }
        }
    }
}

// ---------------- transpose + fp16 convert of fp32 weights (blocked out) ----------------
// in:  W [K][N] fp32 row-major;  out: T blocked [K/8][N][8] fp16
__global__ __launch_bounds__(256) void tconv_kernel(const float* __restrict__ W,
                                                    u16* __restrict__ T,
                                                    int K, int N)
{
    __shared__ float t[32][33];
    int n0 = blockIdx.x * 32, k0 = blockIdx.y * 32;
    int tc = threadIdx.x & 31, tr = threadIdx.x >> 5;   // tr in 0..7
#pragma unroll
    for (int u = 0; u < 4; ++u) {
        int kk = tr + u * 8;
        t[kk][tc] = W[(long long)(k0 + kk) * N + n0 + tc];
    }
    __syncthreads();
#pragma unroll
    for (int u = 0; u < 4; ++u) {
        int nn = tr + u * 8;
        T[OID(N, n0 + nn, k0 + tc)] = f2h(t[tc][nn]);
    }
}

// ---------------- per-layer fused QKV weight prep (blocked fp16 out) ----------------
// wqkv blocked per h: [8][192][8] (rows j: 0-63 q, 64-127 k, 128-191 v; k=d); bias 192/h
__global__ void qkvprep_kernel(const float* __restrict__ wq, const float* __restrict__ wk,
                               const float* __restrict__ wv,
                               const float* __restrict__ bq, const float* __restrict__ bk,
                               const float* __restrict__ bv,
                               u16* __restrict__ wqkv,
                               float* __restrict__ bqkv)
{
    int idx = blockIdx.x * 256 + threadIdx.x;
    if (idx < NH_ * 192 * 64) {
        int d = idx & 63, j = (idx >> 6) % 192, h = idx / (192 * 64);
        int hb = ((h << 6) + d) * 64;
        float v = (j < 64) ? wq[hb + j] : (j < 128) ? wk[hb + (j - 64)] : wv[hb + (j - 128)];
        wqkv[(long long)h * 12288 + ((d >> 3) * 192 + j) * 8 + (d & 7)] = f2h(v);
        return;
    }
    int i3 = idx - NH_ * 192 * 64;
    if (i3 < NH_ * 192) {
        int j = i3 % 192, h = i3 / 192;
        bqkv[i3] = (j < 64) ? bq[(h << 6) + j] : (j < 128) ? bk[(h << 6) + (j - 64)]
                                               : bv[(h << 6) + (j - 128)];
    }
}

// ---------------- zero fill (u32) ----------------
__global__ void zfill_kernel(u32* __restrict__ p, long long n) {
    long long i = (long long)blockIdx.x * 256 + threadIdx.x;
    if (i < n) p[i] = 0u;
}

// ---------------- head GEMM: logits[n][j] = dot(tok_cls[n], w_head[:,j]) + b ----------------
__global__ __launch_bounds__(256) void head_kernel(const float* __restrict__ tok,
                                                   const float* __restrict__ w_head,
                                                   const float* __restrict__ b_head,
                                                   float* __restrict__ logits)
{
    __shared__ float a[D_];
    int n = blockIdx.y;
    int tid = threadIdx.x;
    const float* ar = tok + (long long)n * S_ * D_;    // cls token row
#pragma unroll
    for (int u = 0; u < 3; ++u) a[tid + 256 * u] = ar[tid + 256 * u];
    __syncthreads();
    int j = blockIdx.x * 256 + tid;
    if (j >= OUT_) return;
    float acc = b_head[j];
#pragma unroll 8
    for (int k = 0; k < D_; ++k) acc += a[k] * w_head[(long long)k * OUT_ + j];
    logits[(long long)n * OUT_ + j] = acc;
}

// ---------------- positional embedding ----------------
__global__ void posemb_kernel(float* __restrict__ pos) {
    int idx = blockIdx.x * 256 + threadIdx.x;
    if (idx >= S_ * D_) return;
    int s = idx / D_, d = idx % D_;
    float jj = (float)(d & ~1);
    float freq = powf(10000.0f, jj / (float)D_);
    float arg = (float)s / freq;
    pos[idx] = (d & 1) ? cosf(arg) : sinf(arg);
}

// ---------------- patchify (blocked fp16 out) ----------------
__global__ void patchify_split_kernel(const float* __restrict__ x,
                                      u16* __restrict__ phi) {
    int idx = blockIdx.x * 256 + threadIdx.x;
    if (idx >= B_ * NP_ * NP_ * 768) return;
    int k = idx % 768;
    int row = idx / 768;                  // n*196 + p
    int p = row % (NP_ * NP_);
    int n = row / (NP_ * NP_);
    int c = k >> 8;
    int rem = k & 255;
    int a = rem >> 4;
    int b = rem & 15;
    int i = p / NP_, j = p % NP_;
    float v = x[(((long long)n * C_ + c) * HW_ + (i * PS_ + a)) * HW_ + (j * PS_ + b)];
    phi[OID(B_ * NP_ * NP_, row, k)] = f2h(v);
}

// ---------------- cls token + pos emb ----------------
__global__ void addpos_kernel(float* __restrict__ tok, const float* __restrict__ pos,
                              const float* __restrict__ cls) {
    int idx = blockIdx.x * 256 + threadIdx.x;
    if (idx >= B_ * S_ * D_) return;
    int r = idx % (S_ * D_);
    int s = r / D_, d = r % D_;
    if (s == 0) tok[idx] = cls[d] + pos[d];
    else tok[idx] += pos[r];
}

// ---------------- layernorm, blocked fp16 out ----------------
__global__ __launch_bounds__(256) void ln_split_kernel(const float* __restrict__ x,
                                                       u16* __restrict__ yh,
                                                       const float* __restrict__ g, const float* __restrict__ b) {
    int row = blockIdx.x;
    const float* xr = x + (long long)row * D_;
    int tid = threadIdx.x;
    float v[3];
    float s = 0.f;
#pragma unroll
    for (int u = 0; u < 3; ++u) { v[u] = xr[tid + 256 * u]; s += v[u]; }
    __shared__ float red[256];
    red[tid] = s; __syncthreads();
    for (int off = 128; off > 0; off >>= 1) { if (tid < off) red[tid] += red[tid + off]; __syncthreads(); }
    float mu = red[0] * (1.0f / D_);
    __syncthreads();
    float s2 = 0.f;
#pragma unroll
    for (int u = 0; u < 3; ++u) { float d = v[u] - mu; s2 += d * d; }
    red[tid] = s2; __syncthreads();
    for (int off = 128; off > 0; off >>= 1) { if (tid < off) red[tid] += red[tid + off]; __syncthreads(); }
    float rstd = rsqrtf(red[0] * (1.0f / D_) + 1e-5f);
#pragma unroll
    for (int u = 0; u < 3; ++u) {
        int d = tid + 256 * u;
        float yv = (v[u] - mu) * rstd * g[d] + b[d];
        yh[OID(B_ * S_, row, d)] = f2h(yv);
    }
}

// ---------------- attention softmax: in-place on blocked fp16 ----------------
__global__ __launch_bounds__(64) void att_softmax_kernel(u16* __restrict__ att, float scale) {
    long long rbase = (long long)blockIdx.x * 8;   // row enters OID as row*8
    int tid = threadIdx.x;
    float v[4];
    long long ix[4];
    float mx = -1e30f;
#pragma unroll
    for (int u = 0; u < 4; ++u) {
        int t = tid + 64 * u;
        ix[u] = (long long)(t >> 3) * (NBS_ * 8LL) + rbase + (t & 7);
        v[u] = (t < S_) ? h2f(att[ix[u]]) * scale : -1e30f;
        mx = fmaxf(mx, v[u]);
    }
    for (int off = 32; off > 0; off >>= 1) mx = fmaxf(mx, __shfl_xor(mx, off));
    float sum = 0.f;
#pragma unroll
    for (int u = 0; u < 4; ++u) { v[u] = expf(v[u] - mx); sum += v[u]; }
    for (int off = 32; off > 0; off >>= 1) sum += __shfl_xor(sum, off);
    float inv = 1.0f / sum;
#pragma unroll
    for (int u = 0; u < 4; ++u) {
        int t = tid + 64 * u;
        if (t < S_) att[ix[u]] = f2h(v[u] * inv);
    }
}

// ---------------- head softmax ----------------
__global__ __launch_bounds__(256) void head_softmax_kernel(const float* __restrict__ logits,
                                                           float* __restrict__ out) {
    int n = blockIdx.x;
    const float* p = logits + (long long)n * OUT_;
    int tid = threadIdx.x;
    float v[4];
    float mx = -1e30f;
#pragma unroll
    for (int u = 0; u < 4; ++u) {
        int idx = tid + 256 * u;
        v[u] = (idx < OUT_) ? p[idx] : -1e30f;
        mx = fmaxf(mx, v[u]);
    }
    __shared__ float red[256];
    red[tid] = mx; __syncthreads();
    for (int off = 128; off > 0; off >>= 1) { if (tid < off) red[tid] = fmaxf(red[tid], red[tid + off]); __syncthreads(); }
    mx = red[0];
    __syncthreads();
    float sum = 0.f;
#pragma unroll
    for (int u = 0; u < 4; ++u) { v[u] = expf(v[u] - mx); sum += v[u]; }
    red[tid] = sum; __syncthreads();
    for (int off = 128; off > 0; off >>= 1) { if (tid < off) red[tid] += red[tid + off]; __syncthreads(); }
    float inv = 1.0f / red[0];
#pragma unroll
    for (int u = 0; u < 4; ++u) {
        int idx = tid + 256 * u;
        if (idx < OUT_) out[(long long)n * OUT_ + idx] = v[u] * inv;
    }
}

// ---------------- host helpers ----------------
struct Off { int div; long long so, si; };
static const Off Z0 = {1, 0, 0};

static inline void launch_mfma(hipStream_t st,
                               const u16* Aq, const u16* Bq,
                               const float* bias, float* C, u16* Oq, u16* Oq2,
                               int M, int N, int K, int mplaneA, int mplaneB, int ldc, long long orows,
                               int mode, int accum, int remap, int batch, int ksplit,
                               Off a, Off b, Off c, Off bb) {
    dim3 grid((N + 127) / 128, (M + 127) / 128, batch);
    mfma_gemm_kernel<<<grid, dim3(256), 0, st>>>(Aq, Bq, bias, C, Oq, Oq2,
                                                 M, N, K, mplaneA, mplaneB, ldc, orows,
                                                 mode, accum, remap, ksplit,
                                                 a.div, a.so, a.si, b.div, b.so, b.si,
                                                 c.div, c.so, c.si, bb.div, bb.so, bb.si);
}

extern "C" void kernel_launch(void* const* d_in, const int* in_sizes, int n_in,
                              void* d_out, int out_size, void* d_ws, size_t ws_size,
                              hipStream_t stream) {
    (void)in_sizes; (void)n_in; (void)out_size; (void)ws_size;
    const float* x        = (const float*)d_in[0];
    const float* w_embed  = (const float*)d_in[1];
    const float* b_embed  = (const float*)d_in[2];
    const float* cls_tok  = (const float*)d_in[3];
    const float* ln1_g    = (const float*)d_in[4];
    const float* ln1_b    = (const float*)d_in[5];
    const float* wq       = (const float*)d_in[6];
    const float* bq       = (const float*)d_in[7];
    const float* wk       = (const float*)d_in[8];
    const float* bk       = (const float*)d_in[9];
    const float* wv       = (const float*)d_in[10];
    const float* bv       = (const float*)d_in[11];
    const float* ln2_g    = (const float*)d_in[12];
    const float* ln2_b    = (const float*)d_in[13];
    const float* w1       = (const float*)d_in[14];
    const float* b1       = (const float*)d_in[15];
    const float* w2       = (const float*)d_in[16];
    const float* b2       = (const float*)d_in[17];
    const float* w_head   = (const float*)d_in[18];
    const float* b_head   = (const float*)d_in[19];
    float* out = (float*)d_out;
    char* wsb  = (char*)d_ws;

    const long long TOKSZ = (long long)B_ * S_ * D_;          // 4,841,472
    const int M_TOK = B_ * S_;                                 // 6304
    const int M_PAT = B_ * NP_ * NP_;                          // 6272
    const int NB = B_ * NH_;                                   // 384

    // ---- workspace carve (bytes, 256B aligned) ----
    auto alloc = [&](long long bytes) {
        char* p = wsb;
        wsb += (bytes + 255) & ~255LL;
        return p;
    };
    float* pos    = (float*)alloc((long long)S_ * D_ * 4);
    float* tok    = (float*)alloc(TOKSZ * 4);
    u16*   h_h    = (u16*)alloc(TOKSZ * 2);                    // LN out, blocked [96][M_TOK][8]
    u16*   qk_h   = (u16*)alloc((long long)NH_ * M_TOK * 128 * 2);   // per h: [16][M_TOK][8]
    u16*   vt_h   = (u16*)alloc((long long)SP_ * VROWS_ * 2);  // [28][VROWS][8]
    u16*   w1t    = (u16*)alloc((long long)MLP_ * D_ * 2);     // blocked [96][MLP][8]; wet pre-loop
    u16*   w2t    = (u16*)alloc((long long)D_ * MLP_ * 2);     // blocked [384][768][8]
    u16*   wqkv   = (u16*)alloc((long long)NH_ * 192 * 64 * 2);
    float* bqkv_f = (float*)alloc((long long)NH_ * 192 * 4);
    // big region: max(att 33.9MB, gelu 38.7MB, patches 9.6MB)
    char* bigreg  = alloc((long long)M_TOK * MLP_ * 2);
    u16*   att_h  = (u16*)bigreg;                              // blocked [28][NBS_][8]
    u16*   g_h    = (u16*)bigreg;                              // blocked [384][M_TOK][8]
    u16*   p_h    = (u16*)bigreg;                              // blocked [96][M_PAT][8] pre-loop
    float* logits = (float*)alloc((long long)B_ * OUT_ * 4);

    // ---- embed path ----
    posemb_kernel<<<(S_ * D_ + 255) / 256, 256, 0, stream>>>(pos);
    patchify_split_kernel<<<(M_PAT * 768 + 255) / 256, 256, 0, stream>>>(x, p_h);
    tconv_kernel<<<dim3(768 / 32, 768 / 32), 256, 0, stream>>>(w_embed, w1t, 768, 768);
    launch_mfma(stream, p_h, w1t, b_embed, tok, nullptr, nullptr,
                M_PAT, D_, 768, M_PAT, 768, D_, 0, 0, 0, 1, 1, 1, Z0, Z0, Z0, Z0);
    addpos_kernel<<<((int)TOKSZ + 255) / 256, 256, 0, stream>>>(tok, pos, cls_tok);
    // zero v^T (pads kv in [197,224) must stay 0; live region rewritten each layer)
    {
        long long n32 = (long long)SP_ * VROWS_ / 2;           // u16 count / 2
        zfill_kernel<<<(int)((n32 + 255) / 256), 256, 0, stream>>>((u32*)vt_h, n32);
    }

    const float scale = 0.125f;
    const int QKVPREP_N = NH_ * 192 * 64 + NH_ * 192;

    for (int l = 0; l < L_; ++l) {
        // LN1 -> blocked fp16
        ln_split_kernel<<<M_TOK, 256, 0, stream>>>(tok, h_h, ln1_g + l * D_, ln1_b + l * D_);
        // per-layer fused QKV weight prep (blocked fp16)
        qkvprep_kernel<<<(QKVPREP_N + 255) / 256, 256, 0, stream>>>(
            wq + (long long)l * NH_ * DH_ * DH_, wk + (long long)l * NH_ * DH_ * DH_,
            wv + (long long)l * NH_ * DH_ * DH_,
            bq + (long long)l * NH_ * DH_, bk + (long long)l * NH_ * DH_,
            bv + (long long)l * NH_ * DH_,
            wqkv, bqkv_f);
        // fused Q|K|V: per-head GEMM N=192; epilogue routes q|k -> qk_h, v -> vt_h
        launch_mfma(stream, h_h, wqkv, bqkv_f, nullptr, qk_h, vt_h,
                    M_TOK, 192, 64, M_TOK, 192, 128, M_TOK, 4, 0, 0, NH_, 1,
                    Off{1, (long long)M_TOK * 64, 0}, Off{1, 12288, 0},
                    Z0, Off{1, 192, 0});
        // scores = q @ k^T per (h,n): A = q planes, B = k planes (plane 8 base);
        // out blocked att, cols [197,224) zero-filled
        launch_mfma(stream, qk_h, qk_h + (long long)M_TOK * 64, nullptr, nullptr, att_h, nullptr,
                    S_, S_, 64, M_TOK, M_TOK, SP_, NBS_, 2, 0, 0, NB, 1,
                    Off{B_, (long long)M_TOK * 128, (long long)S_ * 8},
                    Off{B_, (long long)M_TOK * 128, (long long)S_ * 8},
                    Off{1, (long long)S_ * 8, 0}, Z0);
        // softmax in place on blocked fp16
        att_softmax_kernel<<<NB * S_, 64, 0, stream>>>(att_h, scale);
        // O = att @ v  (+residual into tok, fp32 row-major)
        launch_mfma(stream, att_h, vt_h, nullptr, tok, nullptr, nullptr,
                    S_, DH_, SP_, NBS_, VROWS_, D_, 0, 0, 1, 0, NB, 1,
                    Off{1, (long long)S_ * 8, 0},
                    Off{B_, (long long)B_ * DH_ * 8, (long long)DH_ * 8},
                    Off{B_, 64, (long long)S_ * D_}, Z0);
        // LN2 -> blocked fp16
        ln_split_kernel<<<M_TOK, 256, 0, stream>>>(tok, h_h, ln2_g + l * D_, ln2_b + l * D_);
        // weights -> blocked transposed fp16
        tconv_kernel<<<dim3(MLP_ / 32, D_ / 32), 256, 0, stream>>>(
            w1 + (long long)l * D_ * MLP_, w1t, D_, MLP_);
        tconv_kernel<<<dim3(D_ / 32, MLP_ / 32), 256, 0, stream>>>(
            w2 + (long long)l * MLP_ * D_, w2t, MLP_, D_);
        // MLP1: gelu(h @ w1 + b1) -> g blocked fp16
        launch_mfma(stream, h_h, w1t, b1 + (long long)l * MLP_,
                    nullptr, g_h, nullptr, M_TOK, MLP_, D_, M_TOK, MLP_, MLP_, M_TOK, 1, 0, 0, 1, 1,
                    Z0, Z0, Z0, Z0);
        // MLP2: tok += g @ w2 + b2  -- split-K x4: 1200 blocks, atomicAdd epilogue
        launch_mfma(stream, g_h, w2t, b2 + (long long)l * D_,
                    tok, nullptr, nullptr, M_TOK, D_, MLP_, M_TOK, D_, D_, 0, 0, 1, 0, 4, 4,
                    Z0, Z0, Z0, Z0);
    }

    // head: dedicated coalesced kernel (one thread per logit)
    head_kernel<<<dim3((OUT_ + 255) / 256, B_), 256, 0, stream>>>(tok, w_head, b_head, logits);
    head_softmax_kernel<<<B_, 256, 0, stream>>>(logits, out);
}

// Round 10
// 3722.648 us; speedup vs baseline: 1.6937x; 1.6937x over previous
//
#include <hip/hip_runtime.h>
#include <math.h>

// ---------------- dims ----------------
#define B_ 32
#define C_ 3
#define HW_ 224
#define NP_ 14
#define PS_ 16
#define S_ 197        // NP*NP + 1
#define SP_ 224       // S padded to multiple of 32 (kv padding in vt)
#define D_ 768
#define NH_ 12
#define DH_ 64
#define L_ 12
#define MLP_ 3072
#define OUT_ 1000

#define MTOK_ (B_ * S_)               // 6304

// blocked (K-octet-major) layouts: buf[k/8][rows][8] -> fully coalesced
// global_load_lds staging (lane i reads base + i*16B, 1KB burst/instruction).
#define OID(rows, r, k) ((((long long)((k) >> 3)) * (rows) + (r)) * 8 + ((k) & 7))

#define VROWS_ (NH_ * B_ * DH_)       // 24576 rows of vt

typedef unsigned short u16;
typedef unsigned int u32;
typedef __attribute__((ext_vector_type(8))) _Float16 half8_t;
typedef __attribute__((ext_vector_type(4))) float f32x4;
typedef const __attribute__((address_space(1))) u16 gq_t;
typedef __attribute__((address_space(3))) u16 lq_t;

// ---------------- fp16 helpers ----------------
__device__ __forceinline__ u16 f2h(float x) {
    union { _Float16 h; u16 u; } c; c.h = (_Float16)x; return c.u;
}
__device__ __forceinline__ float h2f(u16 u) {
    union { _Float16 h; u16 u; } c; c.u = u; return (float)c.h;
}

// ================= fp16 MFMA GEMM (blocked operands, 3-deep counted-vmcnt pipeline) =================
// (r8 structure — best measured; see comments there)
// mode 0: C[row*ldc+col] = acc+bias (+C_old if accum); remap row=grow+grow/196+1
// mode 1: gelu(acc+bias) -> fp16 at OID(orows, grow, col)
// mode 2: (acc+bias)     -> fp16 at OID(orows, grow, col); zero-fills cols [N,ldc)
// mode 4: fused QKV epilogue (z = head):
//   col<128 -> Oq [z*MTOK_*128 + OID(MTOK_, grow, col)]          (q|k features)
//   col>=128-> Oq2[z*B_*DH_*8 + OID(VROWS_, n*DH_+(col-128), s)] (v transposed)
__global__ __launch_bounds__(256) void mfma_gemm_kernel(
    const u16* __restrict__ Aq, const u16* __restrict__ Bq,
    const float* __restrict__ bias, float* __restrict__ C,
    u16* __restrict__ Oq, u16* __restrict__ Oq2,
    int M, int N, int K, int mplaneA, int mplaneB, int ldc, long long orows,
    int mode, int accum, int remap, int ksplit,
    int divA, long long sAo, long long sAi,
    int divB, long long sBo, long long sBi,
    int divC, long long sCo, long long sCi,
    int divBias, long long sBiaso, long long sBiasi)
{
    __shared__ u16 lds[3][2][4][128][8];   // 48 KB, 3-deep

    int z = blockIdx.z;
    int kz = 0;
    if (ksplit > 1) { kz = z; z = 0; }
    long long aoff = (long long)(z / divA) * sAo + (long long)(z % divA) * sAi;
    long long boff = (long long)(z / divB) * sBo + (long long)(z % divB) * sBi;
    long long coff = (long long)(z / divC) * sCo + (long long)(z % divC) * sCi;
    long long biasoff = (long long)(z / divBias) * sBiaso + (long long)(z % divBias) * sBiasi;

    // ---- bijective XCD-chunked swizzle of the 2D grid (m204) ----
    int nwgx = gridDim.x;
    int nwg = nwgx * gridDim.y;
    int bid = blockIdx.y * nwgx + blockIdx.x;
    int xcd = bid & 7, lid = bid >> 3;
    int qq = nwg >> 3, rr8 = nwg & 7;
    int sw = ((xcd < rr8) ? xcd * (qq + 1) : rr8 * (qq + 1) + (xcd - rr8) * qq) + lid;
    int bx = sw % nwgx, by = sw / nwgx;

    int tid = threadIdx.x;
    int lane = tid & 63;
    int w = tid >> 6;                  // wave id 0..3
    int wm = (w >> 1) * 64, wn = (w & 1) * 64;
    int m0 = by * 128, n0 = bx * 128;
    int lm = lane & 15, qd = lane >> 4;

    // staging role: wave pair (w>>1) -> matrix, (w&1) -> row half
    int smat = w >> 1, shh = w & 1;
    const u16* src = smat ? (Bq + boff) : (Aq + aoff);
    int mp = smat ? mplaneB : mplaneA;
    int sbase = smat ? n0 : m0;
    int srmax = smat ? (N - 1) : (M - 1);
    int sr = sbase + shh * 64 + lane;
    if (sr > srmax) sr = srmax;

    int kc = K / ksplit;
    int kbeg = kz * kc;
    int nsteps = kc / 32;

    auto STAGE = [&](int buf, int k0) {
#pragma unroll
        for (int q = 0; q < 4; ++q) {
            const u16* gp = src + ((long long)((k0 >> 3) + q) * mp + sr) * 8;
            u16* lp = &lds[buf][smat][q][shh * 64][0];
            __builtin_amdgcn_global_load_lds((gq_t*)gp, (lq_t*)lp, 16, 0, 0);
        }
    };

    f32x4 acc[4][4];
#pragma unroll
    for (int i = 0; i < 4; ++i)
#pragma unroll
        for (int j = 0; j < 4; ++j)
            acc[i][j] = (f32x4){0.f, 0.f, 0.f, 0.f};

    STAGE(0, kbeg);
    if (nsteps > 1) STAGE(1, kbeg + 32);
    if (nsteps > 2) STAGE(2, kbeg + 64);

    int cur = 0;
    for (int t = 0; t < nsteps; ++t) {
        int rem = nsteps - 1 - t;
        if (rem >= 2)      asm volatile("s_waitcnt vmcnt(8)" ::: "memory");
        else if (rem == 1) asm volatile("s_waitcnt vmcnt(4)" ::: "memory");
        else               asm volatile("s_waitcnt vmcnt(0)" ::: "memory");
        __builtin_amdgcn_s_barrier();  // B1: all waves' buf-cur loads landed

        half8_t a[4], b[4];
#pragma unroll
        for (int i = 0; i < 4; ++i) {
            a[i] = *(const half8_t*)&lds[cur][0][qd][wm + i * 16 + lm][0];
            b[i] = *(const half8_t*)&lds[cur][1][qd][wn + i * 16 + lm][0];
        }
        asm volatile("s_waitcnt lgkmcnt(0)" ::: "memory");
        __builtin_amdgcn_sched_barrier(0);
        __builtin_amdgcn_s_barrier();  // B2: all waves done reading buf cur

        if (t + 3 < nsteps) STAGE(cur, kbeg + (t + 3) * 32);

#pragma unroll
        for (int i = 0; i < 4; ++i)
#pragma unroll
            for (int j = 0; j < 4; ++j)
                acc[i][j] = __builtin_amdgcn_mfma_f32_16x16x32_f16(a[i], b[j], acc[i][j], 0, 0, 0);

        cur = (cur == 2) ? 0 : cur + 1;
    }

    float* Cb = C ? C + coff : nullptr;
    u16* Ob = Oq ? Oq + coff : nullptr;
    const float* biasb = (bias && kz == 0) ? bias + biasoff : nullptr;

#pragma unroll
    for (int j = 0; j < 4; ++j) {
        int col = n0 + wn + j * 16 + lm;
        bool cok = col < N;
        float bv = (cok && biasb) ? biasb[col] : 0.f;
#pragma unroll
        for (int i = 0; i < 4; ++i) {
#pragma unroll
            for (int r = 0; r < 4; ++r) {
                int grow = m0 + wm + i * 16 + qd * 4 + r;
                if (grow >= M) continue;
                float v = acc[i][j][r] + bv;
                if (mode == 2) {
                    if (col >= ldc) continue;
                    if (!cok) v = 0.f;
                    Ob[OID(orows, grow, col)] = f2h(v);
                } else if (mode == 4) {
                    if (!cok) continue;
                    if (col < 128) {
                        Oq[(long long)z * (MTOK_ * 128LL) + OID(MTOK_, grow, col)] = f2h(v);
                    } else {
                        int nn = grow / S_;
                        int ss = grow - nn * S_;
                        Oq2[(long long)z * (B_ * DH_ * 8LL) + OID(VROWS_, nn * DH_ + (col - 128), ss)] = f2h(v);
                    }
                } else if (mode == 1) {
                    if (!cok) continue;
                    v = 0.5f * v * (1.0f + erff(v * 0.70710678118654752f));
                    Ob[OID(orows, grow, col)] = f2h(v);
                } else {
                    if (!cok) continue;
                    int orow = remap ? (grow + grow / 196 + 1) : grow;
                    long long idx = (long long)orow * ldc + col;
                    if (ksplit > 1) {
                        atomicAdd(&Cb[idx], v);
                    } else {
                        if (accum) v += Cb[idx];
                        Cb[idx] = v;
                    }
                }
            }
        }
    }
}

// ================= fused flash attention: QK^T + online softmax + AV + residual =================
// One block per (n,h); 8 waves x 32 q-rows; no inter-wave sync (wave-private LDS).
// qk: per-head blocked [16 planes][MTOK_][8] (cols 0-63 q, 64-127 k)
// vt: blocked [SP_/8 planes][VROWS_][8], plane=kv octet, row=h*B*64... (per mode 4)
// tok += softmax(q@k^T * scale) @ v   (rows < S_ only; kv cols >= S_ masked)
__global__ __launch_bounds__(512) void attn_kernel(const u16* __restrict__ qk,
                                                   const u16* __restrict__ vt,
                                                   float* __restrict__ tok, float scale)
{
    __shared__ u16 plds[8][8][32][8];   // per-wave P tile: [kv-octet][qrow][8] = 32 KB

    int z = blockIdx.x;
    int n = z / NH_, h = z % NH_;
    int tid = threadIdx.x, lane = tid & 63, w = tid >> 6;
    int lm = lane & 15, qd = lane >> 4;
    int qrow0 = w * 32;

    long long qbase = (long long)h * (MTOK_ * 128LL);
    long long vbase = (long long)h * (B_ * DH_ * 8LL) + (long long)n * DH_ * 8;

    // persistent Q fragments: qf[st][i] rows qrow0+i*16+lm (clamped), plane st*4+qd
    half8_t qf[2][2];
#pragma unroll
    for (int st = 0; st < 2; ++st)
#pragma unroll
        for (int i = 0; i < 2; ++i) {
            int r = qrow0 + i * 16 + lm; if (r > S_ - 1) r = S_ - 1;
            qf[st][i] = *(const half8_t*)&qk[qbase + ((long long)(st * 4 + qd) * MTOK_ + (long long)n * S_ + r) * 8];
        }

    f32x4 oacc[2][4];
#pragma unroll
    for (int i = 0; i < 2; ++i)
#pragma unroll
        for (int j = 0; j < 4; ++j)
            oacc[i][j] = (f32x4){0.f, 0.f, 0.f, 0.f};
    float mrun[2][4], lrun[2][4];
#pragma unroll
    for (int i = 0; i < 2; ++i)
#pragma unroll
        for (int r = 0; r < 4; ++r) { mrun[i][r] = -1e30f; lrun[i][r] = 0.f; }

    for (int c = 0; c < 4; ++c) {
        int kv0 = c * 64;
        // ---- scores chunk: sacc[i][j], rows q, cols kv0+j*16+lm ----
        f32x4 sacc[2][4];
#pragma unroll
        for (int i = 0; i < 2; ++i)
#pragma unroll
            for (int j = 0; j < 4; ++j)
                sacc[i][j] = (f32x4){0.f, 0.f, 0.f, 0.f};
#pragma unroll
        for (int st = 0; st < 2; ++st) {
            half8_t bf[4];
#pragma unroll
            for (int j = 0; j < 4; ++j) {
                int rr = kv0 + j * 16 + lm; if (rr > S_ - 1) rr = S_ - 1;
                bf[j] = *(const half8_t*)&qk[qbase + ((long long)(8 + st * 4 + qd) * MTOK_ + (long long)n * S_ + rr) * 8];
            }
#pragma unroll
            for (int i = 0; i < 2; ++i)
#pragma unroll
                for (int j = 0; j < 4; ++j)
                    sacc[i][j] = __builtin_amdgcn_mfma_f32_16x16x32_f16(qf[st][i], bf[j], sacc[i][j], 0, 0, 0);
        }
        // ---- mask + scale + online softmax (per-row: lanes lm hold the cols) ----
#pragma unroll
        for (int i = 0; i < 2; ++i)
#pragma unroll
            for (int r = 0; r < 4; ++r) {
                float cmax = -1e30f;
#pragma unroll
                for (int j = 0; j < 4; ++j) {
                    float sv = sacc[i][j][r] * scale;
                    if (kv0 + j * 16 + lm >= S_) sv = -1e30f;
                    sacc[i][j][r] = sv;
                    cmax = fmaxf(cmax, sv);
                }
#pragma unroll
                for (int o = 1; o <= 8; o <<= 1) cmax = fmaxf(cmax, __shfl_xor(cmax, o));
                float mn = fmaxf(mrun[i][r], cmax);
                float al = __expf(mrun[i][r] - mn);
                mrun[i][r] = mn;
                lrun[i][r] *= al;
#pragma unroll
                for (int j = 0; j < 4; ++j) oacc[i][j][r] *= al;
                float rs = 0.f;
#pragma unroll
                for (int j = 0; j < 4; ++j) {
                    float p = __expf(sacc[i][j][r] - mn);
                    sacc[i][j][r] = p;
                    rs += p;
                }
#pragma unroll
                for (int o = 1; o <= 8; o <<= 1) rs += __shfl_xor(rs, o);
                lrun[i][r] += rs;
            }
        // ---- P -> wave-private LDS in blocked A-frag layout [kv-octet][qrow][8] ----
#pragma unroll
        for (int i = 0; i < 2; ++i)
#pragma unroll
            for (int j = 0; j < 4; ++j)
#pragma unroll
                for (int r = 0; r < 4; ++r)
                    plds[w][j * 2 + (lm >> 3)][i * 16 + qd * 4 + r][lm & 7] = f2h(sacc[i][j][r]);
        // (same-wave ds_write -> ds_read: compiler inserts lgkmcnt; no barrier needed)
        // ---- AV chunk ----
#pragma unroll
        for (int st = 0; st < 2; ++st) {
            half8_t af[2], bv[4];
#pragma unroll
            for (int i = 0; i < 2; ++i)
                af[i] = *(const half8_t*)&plds[w][st * 4 + qd][i * 16 + lm][0];
            int pl = (kv0 >> 3) + st * 4 + qd;
            if (pl > SP_ / 8 - 1) pl = SP_ / 8 - 1;   // clamped planes are masked by P=0
#pragma unroll
            for (int j = 0; j < 4; ++j)
                bv[j] = *(const half8_t*)&vt[(long long)pl * (VROWS_ * 8LL) + vbase + (long long)(j * 16 + lm) * 8];
#pragma unroll
            for (int i = 0; i < 2; ++i)
#pragma unroll
                for (int j = 0; j < 4; ++j)
                    oacc[i][j] = __builtin_amdgcn_mfma_f32_16x16x32_f16(af[i], bv[j], oacc[i][j], 0, 0, 0);
        }
    }

    // ---- epilogue: tok[n, qrow, h*64+d] += O / l ----
#pragma unroll
    for (int i = 0; i < 2; ++i)
#pragma unroll
        for (int r = 0; r < 4; ++r) {
            int qr = qrow0 + i * 16 + qd * 4 + r;
            if (qr >= S_) continue;
            float inv = 1.0f / lrun[i][r];
#pragma unroll
            for (int j = 0; j < 4; ++j) {
                int d = j * 16 + lm;
                float* tp = &tok[((long long)n * S_ + qr) * D_ + h * 64 + d];
                *tp += oacc[i][j][r] * inv;
            }
        }
}

// ---------------- transpose + fp16 convert of fp32 weights (blocked out) ----------------
__global__ __launch_bounds__(256) void tconv_kernel(const float* __restrict__ W,
                                                    u16* __restrict__ T,
                                                    int K, int N)
{
    __shared__ float t[32][33];
    int n0 = blockIdx.x * 32, k0 = blockIdx.y * 32;
    int tc = threadIdx.x & 31, tr = threadIdx.x >> 5;
#pragma unroll
    for (int u = 0; u < 4; ++u) {
        int kk = tr + u * 8;
        t[kk][tc] = W[(long long)(k0 + kk) * N + n0 + tc];
    }
    __syncthreads();
#pragma unroll
    for (int u = 0; u < 4; ++u) {
        int nn = tr + u * 8;
        T[OID(N, n0 + nn, k0 + tc)] = f2h(t[tc][nn]);
    }
}

// ---------------- per-layer fused QKV weight prep (blocked fp16 out) ----------------
__global__ void qkvprep_kernel(const float* __restrict__ wq, const float* __restrict__ wk,
                               const float* __restrict__ wv,
                               const float* __restrict__ bq, const float* __restrict__ bk,
                               const float* __restrict__ bv,
                               u16* __restrict__ wqkv,
                               float* __restrict__ bqkv)
{
    int idx = blockIdx.x * 256 + threadIdx.x;
    if (idx < NH_ * 192 * 64) {
        int d = idx & 63, j = (idx >> 6) % 192, h = idx / (192 * 64);
        int hb = ((h << 6) + d) * 64;
        float v = (j < 64) ? wq[hb + j] : (j < 128) ? wk[hb + (j - 64)] : wv[hb + (j - 128)];
        wqkv[(long long)h * 12288 + ((d >> 3) * 192 + j) * 8 + (d & 7)] = f2h(v);
        return;
    }
    int i3 = idx - NH_ * 192 * 64;
    if (i3 < NH_ * 192) {
        int j = i3 % 192, h = i3 / 192;
        bqkv[i3] = (j < 64) ? bq[(h << 6) + j] : (j < 128) ? bk[(h << 6) + (j - 64)]
                                               : bv[(h << 6) + (j - 128)];
    }
}

// ---------------- zero fill (u32) ----------------
__global__ void zfill_kernel(u32* __restrict__ p, long long n) {
    long long i = (long long)blockIdx.x * 256 + threadIdx.x;
    if (i < n) p[i] = 0u;
}

// ---------------- head GEMM ----------------
__global__ __launch_bounds__(256) void head_kernel(const float* __restrict__ tok,
                                                   const float* __restrict__ w_head,
                                                   const float* __restrict__ b_head,
                                                   float* __restrict__ logits)
{
    __shared__ float a[D_];
    int n = blockIdx.y;
    int tid = threadIdx.x;
    const float* ar = tok + (long long)n * S_ * D_;
#pragma unroll
    for (int u = 0; u < 3; ++u) a[tid + 256 * u] = ar[tid + 256 * u];
    __syncthreads();
    int j = blockIdx.x * 256 + tid;
    if (j >= OUT_) return;
    float acc = b_head[j];
#pragma unroll 8
    for (int k = 0; k < D_; ++k) acc += a[k] * w_head[(long long)k * OUT_ + j];
    logits[(long long)n * OUT_ + j] = acc;
}

// ---------------- positional embedding ----------------
__global__ void posemb_kernel(float* __restrict__ pos) {
    int idx = blockIdx.x * 256 + threadIdx.x;
    if (idx >= S_ * D_) return;
    int s = idx / D_, d = idx % D_;
    float jj = (float)(d & ~1);
    float freq = powf(10000.0f, jj / (float)D_);
    float arg = (float)s / freq;
    pos[idx] = (d & 1) ? cosf(arg) : sinf(arg);
}

// ---------------- patchify (blocked fp16 out) ----------------
__global__ void patchify_split_kernel(const float* __restrict__ x,
                                      u16* __restrict__ phi) {
    int idx = blockIdx.x * 256 + threadIdx.x;
    if (idx >= B_ * NP_ * NP_ * 768) return;
    int k = idx % 768;
    int row = idx / 768;
    int p = row % (NP_ * NP_);
    int n = row / (NP_ * NP_);
    int c = k >> 8;
    int rem = k & 255;
    int a = rem >> 4;
    int b = rem & 15;
    int i = p / NP_, j = p % NP_;
    float v = x[(((long long)n * C_ + c) * HW_ + (i * PS_ + a)) * HW_ + (j * PS_ + b)];
    phi[OID(B_ * NP_ * NP_, row, k)] = f2h(v);
}

// ---------------- cls token + pos emb ----------------
__global__ void addpos_kernel(float* __restrict__ tok, const float* __restrict__ pos,
                              const float* __restrict__ cls) {
    int idx = blockIdx.x * 256 + threadIdx.x;
    if (idx >= B_ * S_ * D_) return;
    int r = idx % (S_ * D_);
    int s = r / D_, d = r % D_;
    if (s == 0) tok[idx] = cls[d] + pos[d];
    else tok[idx] += pos[r];
}

// ---------------- layernorm, blocked fp16 out ----------------
__global__ __launch_bounds__(256) void ln_split_kernel(const float* __restrict__ x,
                                                       u16* __restrict__ yh,
                                                       const float* __restrict__ g, const float* __restrict__ b) {
    int row = blockIdx.x;
    const float* xr = x + (long long)row * D_;
    int tid = threadIdx.x;
    float v[3];
    float s = 0.f;
#pragma unroll
    for (int u = 0; u < 3; ++u) { v[u] = xr[tid + 256 * u]; s += v[u]; }
    __shared__ float red[256];
    red[tid] = s; __syncthreads();
    for (int off = 128; off > 0; off >>= 1) { if (tid < off) red[tid] += red[tid + off]; __syncthreads(); }
    float mu = red[0] * (1.0f / D_);
    __syncthreads();
    float s2 = 0.f;
#pragma unroll
    for (int u = 0; u < 3; ++u) { float d = v[u] - mu; s2 += d * d; }
    red[tid] = s2; __syncthreads();
    for (int off = 128; off > 0; off >>= 1) { if (tid < off) red[tid] += red[tid + off]; __syncthreads(); }
    float rstd = rsqrtf(red[0] * (1.0f / D_) + 1e-5f);
#pragma unroll
    for (int u = 0; u < 3; ++u) {
        int d = tid + 256 * u;
        float yv = (v[u] - mu) * rstd * g[d] + b[d];
        yh[OID(B_ * S_, row, d)] = f2h(yv);
    }
}

// ---------------- head softmax ----------------
__global__ __launch_bounds__(256) void head_softmax_kernel(const float* __restrict__ logits,
                                                           float* __restrict__ out) {
    int n = blockIdx.x;
    const float* p = logits + (long long)n * OUT_;
    int tid = threadIdx.x;
    float v[4];
    float mx = -1e30f;
#pragma unroll
    for (int u = 0; u < 4; ++u) {
        int idx = tid + 256 * u;
        v[u] = (idx < OUT_) ? p[idx] : -1e30f;
        mx = fmaxf(mx, v[u]);
    }
    __shared__ float red[256];
    red[tid] = mx; __syncthreads();
    for (int off = 128; off > 0; off >>= 1) { if (tid < off) red[tid] = fmaxf(red[tid], red[tid + off]); __syncthreads(); }
    mx = red[0];
    __syncthreads();
    float sum = 0.f;
#pragma unroll
    for (int u = 0; u < 4; ++u) { v[u] = expf(v[u] - mx); sum += v[u]; }
    red[tid] = sum; __syncthreads();
    for (int off = 128; off > 0; off >>= 1) { if (tid < off) red[tid] += red[tid + off]; __syncthreads(); }
    float inv = 1.0f / red[0];
#pragma unroll
    for (int u = 0; u < 4; ++u) {
        int idx = tid + 256 * u;
        if (idx < OUT_) out[(long long)n * OUT_ + idx] = v[u] * inv;
    }
}

// ---------------- host helpers ----------------
struct Off { int div; long long so, si; };
static const Off Z0 = {1, 0, 0};

static inline void launch_mfma(hipStream_t st,
                               const u16* Aq, const u16* Bq,
                               const float* bias, float* C, u16* Oq, u16* Oq2,
                               int M, int N, int K, int mplaneA, int mplaneB, int ldc, long long orows,
                               int mode, int accum, int remap, int batch, int ksplit,
                               Off a, Off b, Off c, Off bb) {
    dim3 grid((N + 127) / 128, (M + 127) / 128, batch);
    mfma_gemm_kernel<<<grid, dim3(256), 0, st>>>(Aq, Bq, bias, C, Oq, Oq2,
                                                 M, N, K, mplaneA, mplaneB, ldc, orows,
                                                 mode, accum, remap, ksplit,
                                                 a.div, a.so, a.si, b.div, b.so, b.si,
                                                 c.div, c.so, c.si, bb.div, bb.so, bb.si);
}

extern "C" void kernel_launch(void* const* d_in, const int* in_sizes, int n_in,
                              void* d_out, int out_size, void* d_ws, size_t ws_size,
                              hipStream_t stream) {
    (void)in_sizes; (void)n_in; (void)out_size; (void)ws_size;
    const float* x        = (const float*)d_in[0];
    const float* w_embed  = (const float*)d_in[1];
    const float* b_embed  = (const float*)d_in[2];
    const float* cls_tok  = (const float*)d_in[3];
    const float* ln1_g    = (const float*)d_in[4];
    const float* ln1_b    = (const float*)d_in[5];
    const float* wq       = (const float*)d_in[6];
    const float* bq       = (const float*)d_in[7];
    const float* wk       = (const float*)d_in[8];
    const float* bk       = (const float*)d_in[9];
    const float* wv       = (const float*)d_in[10];
    const float* bv       = (const float*)d_in[11];
    const float* ln2_g    = (const float*)d_in[12];
    const float* ln2_b    = (const float*)d_in[13];
    const float* w1       = (const float*)d_in[14];
    const float* b1       = (const float*)d_in[15];
    const float* w2       = (const float*)d_in[16];
    const float* b2       = (const float*)d_in[17];
    const float* w_head   = (const float*)d_in[18];
    const float* b_head   = (const float*)d_in[19];
    float* out = (float*)d_out;
    char* wsb  = (char*)d_ws;

    const long long TOKSZ = (long long)B_ * S_ * D_;          // 4,841,472
    const int M_TOK = B_ * S_;                                 // 6304
    const int M_PAT = B_ * NP_ * NP_;                          // 6272

    // ---- workspace carve (bytes, 256B aligned) ----
    auto alloc = [&](long long bytes) {
        char* p = wsb;
        wsb += (bytes + 255) & ~255LL;
        return p;
    };
    float* pos    = (float*)alloc((long long)S_ * D_ * 4);
    float* tok    = (float*)alloc(TOKSZ * 4);
    u16*   h_h    = (u16*)alloc(TOKSZ * 2);                    // LN out, blocked [96][M_TOK][8]
    u16*   qk_h   = (u16*)alloc((long long)NH_ * M_TOK * 128 * 2);   // per h: [16][M_TOK][8]
    u16*   vt_h   = (u16*)alloc((long long)SP_ * VROWS_ * 2);  // [28][VROWS][8]
    u16*   w1t    = (u16*)alloc((long long)MLP_ * D_ * 2);
    u16*   w2t    = (u16*)alloc((long long)D_ * MLP_ * 2);
    u16*   wqkv   = (u16*)alloc((long long)NH_ * 192 * 64 * 2);
    float* bqkv_f = (float*)alloc((long long)NH_ * 192 * 4);
    // big region: max(gelu 38.7MB, patches 9.6MB)
    char* bigreg  = alloc((long long)M_TOK * MLP_ * 2);
    u16*   g_h    = (u16*)bigreg;                              // blocked [384][M_TOK][8]
    u16*   p_h    = (u16*)bigreg;                              // blocked [96][M_PAT][8] pre-loop
    float* logits = (float*)alloc((long long)B_ * OUT_ * 4);

    // ---- embed path ----
    posemb_kernel<<<(S_ * D_ + 255) / 256, 256, 0, stream>>>(pos);
    patchify_split_kernel<<<(M_PAT * 768 + 255) / 256, 256, 0, stream>>>(x, p_h);
    tconv_kernel<<<dim3(768 / 32, 768 / 32), 256, 0, stream>>>(w_embed, w1t, 768, 768);
    launch_mfma(stream, p_h, w1t, b_embed, tok, nullptr, nullptr,
                M_PAT, D_, 768, M_PAT, 768, D_, 0, 0, 0, 1, 1, 1, Z0, Z0, Z0, Z0);
    addpos_kernel<<<((int)TOKSZ + 255) / 256, 256, 0, stream>>>(tok, pos, cls_tok);
    // zero v^T (pads kv in [197,224) must stay 0; live region rewritten each layer)
    {
        long long n32 = (long long)SP_ * VROWS_ / 2;           // u16 count / 2
        zfill_kernel<<<(int)((n32 + 255) / 256), 256, 0, stream>>>((u32*)vt_h, n32);
    }

    const float scale = 0.125f;
    const int QKVPREP_N = NH_ * 192 * 64 + NH_ * 192;

    for (int l = 0; l < L_; ++l) {
        // LN1 -> blocked fp16
        ln_split_kernel<<<M_TOK, 256, 0, stream>>>(tok, h_h, ln1_g + l * D_, ln1_b + l * D_);
        // per-layer fused QKV weight prep (blocked fp16)
        qkvprep_kernel<<<(QKVPREP_N + 255) / 256, 256, 0, stream>>>(
            wq + (long long)l * NH_ * DH_ * DH_, wk + (long long)l * NH_ * DH_ * DH_,
            wv + (long long)l * NH_ * DH_ * DH_,
            bq + (long long)l * NH_ * DH_, bk + (long long)l * NH_ * DH_,
            bv + (long long)l * NH_ * DH_,
            wqkv, bqkv_f);
        // fused Q|K|V: per-head GEMM N=192; epilogue routes q|k -> qk_h, v -> vt_h
        launch_mfma(stream, h_h, wqkv, bqkv_f, nullptr, qk_h, vt_h,
                    M_TOK, 192, 64, M_TOK, 192, 128, M_TOK, 4, 0, 0, NH_, 1,
                    Off{1, (long long)M_TOK * 64, 0}, Off{1, 12288, 0},
                    Z0, Off{1, 192, 0});
        // fused flash attention: QK^T + softmax + AV + residual into tok
        attn_kernel<<<dim3(B_ * NH_), dim3(512), 0, stream>>>(qk_h, vt_h, tok, scale);
        // LN2 -> blocked fp16
        ln_split_kernel<<<M_TOK, 256, 0, stream>>>(tok, h_h, ln2_g + l * D_, ln2_b + l * D_);
        // weights -> blocked transposed fp16
        tconv_kernel<<<dim3(MLP_ / 32, D_ / 32), 256, 0, stream>>>(
            w1 + (long long)l * D_ * MLP_, w1t, D_, MLP_);
        tconv_kernel<<<dim3(D_ / 32, MLP_ / 32), 256, 0, stream>>>(
            w2 + (long long)l * MLP_ * D_, w2t, MLP_, D_);
        // MLP1: gelu(h @ w1 + b1) -> g blocked fp16
        launch_mfma(stream, h_h, w1t, b1 + (long long)l * MLP_,
                    nullptr, g_h, nullptr, M_TOK, MLP_, D_, M_TOK, MLP_, MLP_, M_TOK, 1, 0, 0, 1, 1,
                    Z0, Z0, Z0, Z0);
        // MLP2: tok += g @ w2 + b2  -- split-K x4: 1200 blocks, atomicAdd epilogue
        launch_mfma(stream, g_h, w2t, b2 + (long long)l * D_,
                    tok, nullptr, nullptr, M_TOK, D_, MLP_, M_TOK, D_, D_, 0, 0, 1, 0, 4, 4,
                    Z0, Z0, Z0, Z0);
    }

    // head: dedicated coalesced kernel (one thread per logit)
    head_kernel<<<dim3((OUT_ + 255) / 256, B_), 256, 0, stream>>>(tok, w_head, b_head, logits);
    head_softmax_kernel<<<B_, 256, 0, stream>>>(logits, out);
}

// Round 11
// 3643.826 us; speedup vs baseline: 1.7303x; 1.0216x over previous
//
#include <hip/hip_runtime.h>
#include <math.h>

// ---------------- dims ----------------
#define B_ 32
#define C_ 3
#define HW_ 224
#define NP_ 14
#define PS_ 16
#define S_ 197        // NP*NP + 1
#define SP_ 224       // S padded to multiple of 32 (kv padding in vt)
#define D_ 768
#define NH_ 12
#define DH_ 64
#define L_ 12
#define MLP_ 3072
#define OUT_ 1000

#define MTOK_ (B_ * S_)               // 6304

// blocked (K-octet-major) layouts: buf[k/8][rows][8] -> fully coalesced
// global_load_lds staging (lane i reads base + i*16B, 1KB burst/instruction).
#define OID(rows, r, k) ((((long long)((k) >> 3)) * (rows) + (r)) * 8 + ((k) & 7))

#define VROWS_ (NH_ * B_ * DH_)       // 24576 rows of vt

typedef unsigned short u16;
typedef unsigned int u32;
typedef __attribute__((ext_vector_type(8))) _Float16 half8_t;
typedef __attribute__((ext_vector_type(4))) float f32x4;
typedef const __attribute__((address_space(1))) u16 gq_t;
typedef __attribute__((address_space(3))) u16 lq_t;

// ---------------- fp16 helpers ----------------
__device__ __forceinline__ u16 f2h(float x) {
    union { _Float16 h; u16 u; } c; c.h = (_Float16)x; return c.u;
}
__device__ __forceinline__ float h2f(u16 u) {
    union { _Float16 h; u16 u; } c; c.u = u; return (float)c.h;
}

// ================= fp16 MFMA GEMM (blocked operands, 2-deep 32KB counted-vmcnt pipeline) =================
// C = A @ B^T(stored blocked [K/8][rowsN][8]), fp16 inputs, fp32 accumulate.
// 2 LDS buffers (32 KB -> 5 blocks/CU, 20 waves/CU); loads stay in flight across
// barriers (steady-state s_waitcnt vmcnt(4), never 0 until the tail). Two raw
// s_barriers per step:
//   B1 after own-vmcnt wait -> all waves' loads for buf cur landed
//   B2 after lgkmcnt(0)     -> all waves done READING buf cur (safe to restage)
// Per-z offsets: off = (z/div)*so + (z%div)*si (element offsets into blocked bufs).
// ksplit>1: blockIdx.z = K chunk; epilogue atomicAdd into C; bias only chunk 0.
// mode 0: C[row*ldc+col] = acc+bias (+C_old if accum); remap row=grow+grow/196+1
// mode 1: gelu(acc+bias) -> fp16 at OID(orows, grow, col)
// mode 2: (acc+bias)     -> fp16 at OID(orows, grow, col); zero-fills cols [N,ldc)
// mode 4: fused QKV epilogue (z = head):
//   col<128 -> Oq [z*MTOK_*128 + OID(MTOK_, grow, col)]          (q|k features)
//   col>=128-> Oq2[z*B_*DH_*8 + OID(VROWS_, n*DH_+(col-128), s)] (v transposed)
__global__ __launch_bounds__(256) void mfma_gemm_kernel(
    const u16* __restrict__ Aq, const u16* __restrict__ Bq,
    const float* __restrict__ bias, float* __restrict__ C,
    u16* __restrict__ Oq, u16* __restrict__ Oq2,
    int M, int N, int K, int mplaneA, int mplaneB, int ldc, long long orows,
    int mode, int accum, int remap, int ksplit,
    int divA, long long sAo, long long sAi,
    int divB, long long sBo, long long sBi,
    int divC, long long sCo, long long sCi,
    int divBias, long long sBiaso, long long sBiasi)
{
    __shared__ u16 lds[2][2][4][128][8];   // 32 KB, 2-deep

    int z = blockIdx.z;
    int kz = 0;
    if (ksplit > 1) { kz = z; z = 0; }
    long long aoff = (long long)(z / divA) * sAo + (long long)(z % divA) * sAi;
    long long boff = (long long)(z / divB) * sBo + (long long)(z % divB) * sBi;
    long long coff = (long long)(z / divC) * sCo + (long long)(z % divC) * sCi;
    long long biasoff = (long long)(z / divBias) * sBiaso + (long long)(z % divBias) * sBiasi;

    // ---- bijective XCD-chunked swizzle of the 2D grid (m204) ----
    int nwgx = gridDim.x;
    int nwg = nwgx * gridDim.y;
    int bid = blockIdx.y * nwgx + blockIdx.x;
    int xcd = bid & 7, lid = bid >> 3;
    int qq = nwg >> 3, rr8 = nwg & 7;
    int sw = ((xcd < rr8) ? xcd * (qq + 1) : rr8 * (qq + 1) + (xcd - rr8) * qq) + lid;
    int bx = sw % nwgx, by = sw / nwgx;

    int tid = threadIdx.x;
    int lane = tid & 63;
    int w = tid >> 6;                  // wave id 0..3
    int wm = (w >> 1) * 64, wn = (w & 1) * 64;
    int m0 = by * 128, n0 = bx * 128;
    int lm = lane & 15, qd = lane >> 4;

    // staging role: wave pair (w>>1) -> matrix, (w&1) -> row half
    int smat = w >> 1, shh = w & 1;
    const u16* src = smat ? (Bq + boff) : (Aq + aoff);
    int mp = smat ? mplaneB : mplaneA;
    int sbase = smat ? n0 : m0;
    int srmax = smat ? (N - 1) : (M - 1);
    int sr = sbase + shh * 64 + lane;
    if (sr > srmax) sr = srmax;

    int kc = K / ksplit;
    int kbeg = kz * kc;
    int nsteps = kc / 32;

    auto STAGE = [&](int buf, int k0) {
#pragma unroll
        for (int q = 0; q < 4; ++q) {
            const u16* gp = src + ((long long)((k0 >> 3) + q) * mp + sr) * 8;
            u16* lp = &lds[buf][smat][q][shh * 64][0];
            __builtin_amdgcn_global_load_lds((gq_t*)gp, (lq_t*)lp, 16, 0, 0);
        }
    };

    f32x4 acc[4][4];
#pragma unroll
    for (int i = 0; i < 4; ++i)
#pragma unroll
        for (int j = 0; j < 4; ++j)
            acc[i][j] = (f32x4){0.f, 0.f, 0.f, 0.f};

    STAGE(0, kbeg);
    if (nsteps > 1) STAGE(1, kbeg + 32);

    int cur = 0;
    for (int t = 0; t < nsteps; ++t) {
        // wait for OWN 4 loads of buf cur (next tile's 4 stay in flight)
        if (t < nsteps - 1) asm volatile("s_waitcnt vmcnt(4)" ::: "memory");
        else                asm volatile("s_waitcnt vmcnt(0)" ::: "memory");
        __builtin_amdgcn_s_barrier();  // B1: all waves' buf-cur loads landed

        half8_t a[4], b[4];
#pragma unroll
        for (int i = 0; i < 4; ++i) {
            a[i] = *(const half8_t*)&lds[cur][0][qd][wm + i * 16 + lm][0];
            b[i] = *(const half8_t*)&lds[cur][1][qd][wn + i * 16 + lm][0];
        }
        asm volatile("s_waitcnt lgkmcnt(0)" ::: "memory");
        __builtin_amdgcn_sched_barrier(0);
        __builtin_amdgcn_s_barrier();  // B2: all waves done reading buf cur

        if (t + 2 < nsteps) STAGE(cur, kbeg + (t + 2) * 32); // refill under MFMAs

#pragma unroll
        for (int i = 0; i < 4; ++i)
#pragma unroll
            for (int j = 0; j < 4; ++j)
                acc[i][j] = __builtin_amdgcn_mfma_f32_16x16x32_f16(a[i], b[j], acc[i][j], 0, 0, 0);

        cur ^= 1;
    }

    float* Cb = C ? C + coff : nullptr;
    u16* Ob = Oq ? Oq + coff : nullptr;
    const float* biasb = (bias && kz == 0) ? bias + biasoff : nullptr;

#pragma unroll
    for (int j = 0; j < 4; ++j) {
        int col = n0 + wn + j * 16 + lm;
        bool cok = col < N;
        float bv = (cok && biasb) ? biasb[col] : 0.f;
#pragma unroll
        for (int i = 0; i < 4; ++i) {
#pragma unroll
            for (int r = 0; r < 4; ++r) {
                int grow = m0 + wm + i * 16 + qd * 4 + r;
                if (grow >= M) continue;
                float v = acc[i][j][r] + bv;
                if (mode == 2) {
                    if (col >= ldc) continue;
                    if (!cok) v = 0.f;
                    Ob[OID(orows, grow, col)] = f2h(v);
                } else if (mode == 4) {
                    if (!cok) continue;
                    if (col < 128) {
                        Oq[(long long)z * (MTOK_ * 128LL) + OID(MTOK_, grow, col)] = f2h(v);
                    } else {
                        int nn = grow / S_;
                        int ss = grow - nn * S_;
                        Oq2[(long long)z * (B_ * DH_ * 8LL) + OID(VROWS_, nn * DH_ + (col - 128), ss)] = f2h(v);
                    }
                } else if (mode == 1) {
                    if (!cok) continue;
                    v = 0.5f * v * (1.0f + erff(v * 0.70710678118654752f));
                    Ob[OID(orows, grow, col)] = f2h(v);
                } else {
                    if (!cok) continue;
                    int orow = remap ? (grow + grow / 196 + 1) : grow;
                    long long idx = (long long)orow * ldc + col;
                    if (ksplit > 1) {
                        atomicAdd(&Cb[idx], v);
                    } else {
                        if (accum) v += Cb[idx];
                        Cb[idx] = v;
                    }
                }
            }
        }
    }
}

// ================= fused flash attention: QK^T + online softmax + AV + residual =================
// One block per (n,h); 8 waves x 32 q-rows; no inter-wave sync (wave-private LDS).
__global__ __launch_bounds__(512) void attn_kernel(const u16* __restrict__ qk,
                                                   const u16* __restrict__ vt,
                                                   float* __restrict__ tok, float scale)
{
    __shared__ u16 plds[8][8][32][8];   // per-wave P tile: [kv-octet][qrow][8] = 32 KB

    int z = blockIdx.x;
    int n = z / NH_, h = z % NH_;
    int tid = threadIdx.x, lane = tid & 63, w = tid >> 6;
    int lm = lane & 15, qd = lane >> 4;
    int qrow0 = w * 32;

    long long qbase = (long long)h * (MTOK_ * 128LL);
    long long vbase = (long long)h * (B_ * DH_ * 8LL) + (long long)n * DH_ * 8;

    half8_t qf[2][2];
#pragma unroll
    for (int st = 0; st < 2; ++st)
#pragma unroll
        for (int i = 0; i < 2; ++i) {
            int r = qrow0 + i * 16 + lm; if (r > S_ - 1) r = S_ - 1;
            qf[st][i] = *(const half8_t*)&qk[qbase + ((long long)(st * 4 + qd) * MTOK_ + (long long)n * S_ + r) * 8];
        }

    f32x4 oacc[2][4];
#pragma unroll
    for (int i = 0; i < 2; ++i)
#pragma unroll
        for (int j = 0; j < 4; ++j)
            oacc[i][j] = (f32x4){0.f, 0.f, 0.f, 0.f};
    float mrun[2][4], lrun[2][4];
#pragma unroll
    for (int i = 0; i < 2; ++i)
#pragma unroll
        for (int r = 0; r < 4; ++r) { mrun[i][r] = -1e30f; lrun[i][r] = 0.f; }

    for (int c = 0; c < 4; ++c) {
        int kv0 = c * 64;
        f32x4 sacc[2][4];
#pragma unroll
        for (int i = 0; i < 2; ++i)
#pragma unroll
            for (int j = 0; j < 4; ++j)
                sacc[i][j] = (f32x4){0.f, 0.f, 0.f, 0.f};
#pragma unroll
        for (int st = 0; st < 2; ++st) {
            half8_t bf[4];
#pragma unroll
            for (int j = 0; j < 4; ++j) {
                int rr = kv0 + j * 16 + lm; if (rr > S_ - 1) rr = S_ - 1;
                bf[j] = *(const half8_t*)&qk[qbase + ((long long)(8 + st * 4 + qd) * MTOK_ + (long long)n * S_ + rr) * 8];
            }
#pragma unroll
            for (int i = 0; i < 2; ++i)
#pragma unroll
                for (int j = 0; j < 4; ++j)
                    sacc[i][j] = __builtin_amdgcn_mfma_f32_16x16x32_f16(qf[st][i], bf[j], sacc[i][j], 0, 0, 0);
        }
#pragma unroll
        for (int i = 0; i < 2; ++i)
#pragma unroll
            for (int r = 0; r < 4; ++r) {
                float cmax = -1e30f;
#pragma unroll
                for (int j = 0; j < 4; ++j) {
                    float sv = sacc[i][j][r] * scale;
                    if (kv0 + j * 16 + lm >= S_) sv = -1e30f;
                    sacc[i][j][r] = sv;
                    cmax = fmaxf(cmax, sv);
                }
#pragma unroll
                for (int o = 1; o <= 8; o <<= 1) cmax = fmaxf(cmax, __shfl_xor(cmax, o));
                float mn = fmaxf(mrun[i][r], cmax);
                float al = __expf(mrun[i][r] - mn);
                mrun[i][r] = mn;
                lrun[i][r] *= al;
#pragma unroll
                for (int j = 0; j < 4; ++j) oacc[i][j][r] *= al;
                float rs = 0.f;
#pragma unroll
                for (int j = 0; j < 4; ++j) {
                    float p = __expf(sacc[i][j][r] - mn);
                    sacc[i][j][r] = p;
                    rs += p;
                }
#pragma unroll
                for (int o = 1; o <= 8; o <<= 1) rs += __shfl_xor(rs, o);
                lrun[i][r] += rs;
            }
#pragma unroll
        for (int i = 0; i < 2; ++i)
#pragma unroll
            for (int j = 0; j < 4; ++j)
#pragma unroll
                for (int r = 0; r < 4; ++r)
                    plds[w][j * 2 + (lm >> 3)][i * 16 + qd * 4 + r][lm & 7] = f2h(sacc[i][j][r]);
#pragma unroll
        for (int st = 0; st < 2; ++st) {
            half8_t af[2], bv[4];
#pragma unroll
            for (int i = 0; i < 2; ++i)
                af[i] = *(const half8_t*)&plds[w][st * 4 + qd][i * 16 + lm][0];
            int pl = (kv0 >> 3) + st * 4 + qd;
            if (pl > SP_ / 8 - 1) pl = SP_ / 8 - 1;
#pragma unroll
            for (int j = 0; j < 4; ++j)
                bv[j] = *(const half8_t*)&vt[(long long)pl * (VROWS_ * 8LL) + vbase + (long long)(j * 16 + lm) * 8];
#pragma unroll
            for (int i = 0; i < 2; ++i)
#pragma unroll
                for (int j = 0; j < 4; ++j)
                    oacc[i][j] = __builtin_amdgcn_mfma_f32_16x16x32_f16(af[i], bv[j], oacc[i][j], 0, 0, 0);
        }
    }

#pragma unroll
    for (int i = 0; i < 2; ++i)
#pragma unroll
        for (int r = 0; r < 4; ++r) {
            int qr = qrow0 + i * 16 + qd * 4 + r;
            if (qr >= S_) continue;
            float inv = 1.0f / lrun[i][r];
#pragma unroll
            for (int j = 0; j < 4; ++j) {
                int d = j * 16 + lm;
                float* tp = &tok[((long long)n * S_ + qr) * D_ + h * 64 + d];
                *tp += oacc[i][j][r] * inv;
            }
        }
}

// ---------------- transpose + fp16 convert of fp32 weights (blocked out) ----------------
__global__ __launch_bounds__(256) void tconv_kernel(const float* __restrict__ W,
                                                    u16* __restrict__ T,
                                                    int K, int N)
{
    __shared__ float t[32][33];
    int n0 = blockIdx.x * 32, k0 = blockIdx.y * 32;
    int tc = threadIdx.x & 31, tr = threadIdx.x >> 5;
#pragma unroll
    for (int u = 0; u < 4; ++u) {
        int kk = tr + u * 8;
        t[kk][tc] = W[(long long)(k0 + kk) * N + n0 + tc];
    }
    __syncthreads();
#pragma unroll
    for (int u = 0; u < 4; ++u) {
        int nn = tr + u * 8;
        T[OID(N, n0 + nn, k0 + tc)] = f2h(t[tc][nn]);
    }
}

// ---------------- per-layer fused QKV weight prep (blocked fp16 out) ----------------
__global__ void qkvprep_kernel(const float* __restrict__ wq, const float* __restrict__ wk,
                               const float* __restrict__ wv,
                               const float* __restrict__ bq, const float* __restrict__ bk,
                               const float* __restrict__ bv,
                               u16* __restrict__ wqkv,
                               float* __restrict__ bqkv)
{
    int idx = blockIdx.x * 256 + threadIdx.x;
    if (idx < NH_ * 192 * 64) {
        int d = idx & 63, j = (idx >> 6) % 192, h = idx / (192 * 64);
        int hb = ((h << 6) + d) * 64;
        float v = (j < 64) ? wq[hb + j] : (j < 128) ? wk[hb + (j - 64)] : wv[hb + (j - 128)];
        wqkv[(long long)h * 12288 + ((d >> 3) * 192 + j) * 8 + (d & 7)] = f2h(v);
        return;
    }
    int i3 = idx - NH_ * 192 * 64;
    if (i3 < NH_ * 192) {
        int j = i3 % 192, h = i3 / 192;
        bqkv[i3] = (j < 64) ? bq[(h << 6) + j] : (j < 128) ? bk[(h << 6) + (j - 64)]
                                               : bv[(h << 6) + (j - 128)];
    }
}

// ---------------- zero fill (u32) ----------------
__global__ void zfill_kernel(u32* __restrict__ p, long long n) {
    long long i = (long long)blockIdx.x * 256 + threadIdx.x;
    if (i < n) p[i] = 0u;
}

// ---------------- head GEMM ----------------
__global__ __launch_bounds__(256) void head_kernel(const float* __restrict__ tok,
                                                   const float* __restrict__ w_head,
                                                   const float* __restrict__ b_head,
                                                   float* __restrict__ logits)
{
    __shared__ float a[D_];
    int n = blockIdx.y;
    int tid = threadIdx.x;
    const float* ar = tok + (long long)n * S_ * D_;
#pragma unroll
    for (int u = 0; u < 3; ++u) a[tid + 256 * u] = ar[tid + 256 * u];
    __syncthreads();
    int j = blockIdx.x * 256 + tid;
    if (j >= OUT_) return;
    float acc = b_head[j];
#pragma unroll 8
    for (int k = 0; k < D_; ++k) acc += a[k] * w_head[(long long)k * OUT_ + j];
    logits[(long long)n * OUT_ + j] = acc;
}

// ---------------- positional embedding ----------------
__global__ void posemb_kernel(float* __restrict__ pos) {
    int idx = blockIdx.x * 256 + threadIdx.x;
    if (idx >= S_ * D_) return;
    int s = idx / D_, d = idx % D_;
    float jj = (float)(d & ~1);
    float freq = powf(10000.0f, jj / (float)D_);
    float arg = (float)s / freq;
    pos[idx] = (d & 1) ? cosf(arg) : sinf(arg);
}

// ---------------- patchify (blocked fp16 out) ----------------
__global__ void patchify_split_kernel(const float* __restrict__ x,
                                      u16* __restrict__ phi) {
    int idx = blockIdx.x * 256 + threadIdx.x;
    if (idx >= B_ * NP_ * NP_ * 768) return;
    int k = idx % 768;
    int row = idx / 768;
    int p = row % (NP_ * NP_);
    int n = row / (NP_ * NP_);
    int c = k >> 8;
    int rem = k & 255;
    int a = rem >> 4;
    int b = rem & 15;
    int i = p / NP_, j = p % NP_;
    float v = x[(((long long)n * C_ + c) * HW_ + (i * PS_ + a)) * HW_ + (j * PS_ + b)];
    phi[OID(B_ * NP_ * NP_, row, k)] = f2h(v);
}

// ---------------- cls token + pos emb ----------------
__global__ void addpos_kernel(float* __restrict__ tok, const float* __restrict__ pos,
                              const float* __restrict__ cls) {
    int idx = blockIdx.x * 256 + threadIdx.x;
    if (idx >= B_ * S_ * D_) return;
    int r = idx % (S_ * D_);
    int s = r / D_, d = r % D_;
    if (s == 0) tok[idx] = cls[d] + pos[d];
    else tok[idx] += pos[r];
}

// ---------------- layernorm, blocked fp16 out (wave-shuffle reduction) ----------------
__global__ __launch_bounds__(256) void ln_split_kernel(const float* __restrict__ x,
                                                       u16* __restrict__ yh,
                                                       const float* __restrict__ g, const float* __restrict__ b) {
    int row = blockIdx.x;
    const float* xr = x + (long long)row * D_;
    int tid = threadIdx.x, lane = tid & 63, w = tid >> 6;
    __shared__ float red[2][4];
    float v[3];
    float s = 0.f;
#pragma unroll
    for (int u = 0; u < 3; ++u) { v[u] = xr[tid + 256 * u]; s += v[u]; }
#pragma unroll
    for (int o = 1; o <= 32; o <<= 1) s += __shfl_xor(s, o);
    if (lane == 0) red[0][w] = s;
    __syncthreads();
    float mu = (red[0][0] + red[0][1] + red[0][2] + red[0][3]) * (1.0f / D_);
    float s2 = 0.f;
#pragma unroll
    for (int u = 0; u < 3; ++u) { float d = v[u] - mu; s2 += d * d; }
#pragma unroll
    for (int o = 1; o <= 32; o <<= 1) s2 += __shfl_xor(s2, o);
    if (lane == 0) red[1][w] = s2;
    __syncthreads();
    float rstd = rsqrtf((red[1][0] + red[1][1] + red[1][2] + red[1][3]) * (1.0f / D_) + 1e-5f);
#pragma unroll
    for (int u = 0; u < 3; ++u) {
        int d = tid + 256 * u;
        float yv = (v[u] - mu) * rstd * g[d] + b[d];
        yh[OID(B_ * S_, row, d)] = f2h(yv);
    }
}

// ---------------- head softmax ----------------
__global__ __launch_bounds__(256) void head_softmax_kernel(const float* __restrict__ logits,
                                                           float* __restrict__ out) {
    int n = blockIdx.x;
    const float* p = logits + (long long)n * OUT_;
    int tid = threadIdx.x;
    float v[4];
    float mx = -1e30f;
#pragma unroll
    for (int u = 0; u < 4; ++u) {
        int idx = tid + 256 * u;
        v[u] = (idx < OUT_) ? p[idx] : -1e30f;
        mx = fmaxf(mx, v[u]);
    }
    __shared__ float red[256];
    red[tid] = mx; __syncthreads();
    for (int off = 128; off > 0; off >>= 1) { if (tid < off) red[tid] = fmaxf(red[tid], red[tid + off]); __syncthreads(); }
    mx = red[0];
    __syncthreads();
    float sum = 0.f;
#pragma unroll
    for (int u = 0; u < 4; ++u) { v[u] = expf(v[u] - mx); sum += v[u]; }
    red[tid] = sum; __syncthreads();
    for (int off = 128; off > 0; off >>= 1) { if (tid < off) red[tid] += red[tid + off]; __syncthreads(); }
    float inv = 1.0f / red[0];
#pragma unroll
    for (int u = 0; u < 4; ++u) {
        int idx = tid + 256 * u;
        if (idx < OUT_) out[(long long)n * OUT_ + idx] = v[u] * inv;
    }
}

// ---------------- host helpers ----------------
struct Off { int div; long long so, si; };
static const Off Z0 = {1, 0, 0};

static inline void launch_mfma(hipStream_t st,
                               const u16* Aq, const u16* Bq,
                               const float* bias, float* C, u16* Oq, u16* Oq2,
                               int M, int N, int K, int mplaneA, int mplaneB, int ldc, long long orows,
                               int mode, int accum, int remap, int batch, int ksplit,
                               Off a, Off b, Off c, Off bb) {
    dim3 grid((N + 127) / 128, (M + 127) / 128, batch);
    mfma_gemm_kernel<<<grid, dim3(256), 0, st>>>(Aq, Bq, bias, C, Oq, Oq2,
                                                 M, N, K, mplaneA, mplaneB, ldc, orows,
                                                 mode, accum, remap, ksplit,
                                                 a.div, a.so, a.si, b.div, b.so, b.si,
                                                 c.div, c.so, c.si, bb.div, bb.so, bb.si);
}

extern "C" void kernel_launch(void* const* d_in, const int* in_sizes, int n_in,
                              void* d_out, int out_size, void* d_ws, size_t ws_size,
                              hipStream_t stream) {
    (void)in_sizes; (void)n_in; (void)out_size; (void)ws_size;
    const float* x        = (const float*)d_in[0];
    const float* w_embed  = (const float*)d_in[1];
    const float* b_embed  = (const float*)d_in[2];
    const float* cls_tok  = (const float*)d_in[3];
    const float* ln1_g    = (const float*)d_in[4];
    const float* ln1_b    = (const float*)d_in[5];
    const float* wq       = (const float*)d_in[6];
    const float* bq       = (const float*)d_in[7];
    const float* wk       = (const float*)d_in[8];
    const float* bk       = (const float*)d_in[9];
    const float* wv       = (const float*)d_in[10];
    const float* bv       = (const float*)d_in[11];
    const float* ln2_g    = (const float*)d_in[12];
    const float* ln2_b    = (const float*)d_in[13];
    const float* w1       = (const float*)d_in[14];
    const float* b1       = (const float*)d_in[15];
    const float* w2       = (const float*)d_in[16];
    const float* b2       = (const float*)d_in[17];
    const float* w_head   = (const float*)d_in[18];
    const float* b_head   = (const float*)d_in[19];
    float* out = (float*)d_out;
    char* wsb  = (char*)d_ws;

    const long long TOKSZ = (long long)B_ * S_ * D_;          // 4,841,472
    const int M_TOK = B_ * S_;                                 // 6304
    const int M_PAT = B_ * NP_ * NP_;                          // 6272

    // ---- workspace carve (bytes, 256B aligned) ----
    auto alloc = [&](long long bytes) {
        char* p = wsb;
        wsb += (bytes + 255) & ~255LL;
        return p;
    };
    float* pos    = (float*)alloc((long long)S_ * D_ * 4);
    float* tok    = (float*)alloc(TOKSZ * 4);
    u16*   h_h    = (u16*)alloc(TOKSZ * 2);                    // LN out, blocked [96][M_TOK][8]
    u16*   qk_h   = (u16*)alloc((long long)NH_ * M_TOK * 128 * 2);   // per h: [16][M_TOK][8]
    u16*   vt_h   = (u16*)alloc((long long)SP_ * VROWS_ * 2);  // [28][VROWS][8]
    u16*   w1t    = (u16*)alloc((long long)MLP_ * D_ * 2);
    u16*   w2t    = (u16*)alloc((long long)D_ * MLP_ * 2);
    u16*   wqkv   = (u16*)alloc((long long)NH_ * 192 * 64 * 2);
    float* bqkv_f = (float*)alloc((long long)NH_ * 192 * 4);
    // big region: max(gelu 38.7MB, patches 9.6MB)
    char* bigreg  = alloc((long long)M_TOK * MLP_ * 2);
    u16*   g_h    = (u16*)bigreg;                              // blocked [384][M_TOK][8]
    u16*   p_h    = (u16*)bigreg;                              // blocked [96][M_PAT][8] pre-loop
    float* logits = (float*)alloc((long long)B_ * OUT_ * 4);

    // ---- embed path ----
    posemb_kernel<<<(S_ * D_ + 255) / 256, 256, 0, stream>>>(pos);
    patchify_split_kernel<<<(M_PAT * 768 + 255) / 256, 256, 0, stream>>>(x, p_h);
    tconv_kernel<<<dim3(768 / 32, 768 / 32), 256, 0, stream>>>(w_embed, w1t, 768, 768);
    launch_mfma(stream, p_h, w1t, b_embed, tok, nullptr, nullptr,
                M_PAT, D_, 768, M_PAT, 768, D_, 0, 0, 0, 1, 1, 1, Z0, Z0, Z0, Z0);
    addpos_kernel<<<((int)TOKSZ + 255) / 256, 256, 0, stream>>>(tok, pos, cls_tok);
    // zero v^T (pads kv in [197,224) must stay 0; live region rewritten each layer)
    {
        long long n32 = (long long)SP_ * VROWS_ / 2;           // u16 count / 2
        zfill_kernel<<<(int)((n32 + 255) / 256), 256, 0, stream>>>((u32*)vt_h, n32);
    }

    const float scale = 0.125f;
    const int QKVPREP_N = NH_ * 192 * 64 + NH_ * 192;

    for (int l = 0; l < L_; ++l) {
        // LN1 -> blocked fp16
        ln_split_kernel<<<M_TOK, 256, 0, stream>>>(tok, h_h, ln1_g + l * D_, ln1_b + l * D_);
        // per-layer fused QKV weight prep (blocked fp16)
        qkvprep_kernel<<<(QKVPREP_N + 255) / 256, 256, 0, stream>>>(
            wq + (long long)l * NH_ * DH_ * DH_, wk + (long long)l * NH_ * DH_ * DH_,
            wv + (long long)l * NH_ * DH_ * DH_,
            bq + (long long)l * NH_ * DH_, bk + (long long)l * NH_ * DH_,
            bv + (long long)l * NH_ * DH_,
            wqkv, bqkv_f);
        // fused Q|K|V: per-head GEMM N=192; epilogue routes q|k -> qk_h, v -> vt_h
        launch_mfma(stream, h_h, wqkv, bqkv_f, nullptr, qk_h, vt_h,
                    M_TOK, 192, 64, M_TOK, 192, 128, M_TOK, 4, 0, 0, NH_, 1,
                    Off{1, (long long)M_TOK * 64, 0}, Off{1, 12288, 0},
                    Z0, Off{1, 192, 0});
        // fused flash attention: QK^T + softmax + AV + residual into tok
        attn_kernel<<<dim3(B_ * NH_), dim3(512), 0, stream>>>(qk_h, vt_h, tok, scale);
        // LN2 -> blocked fp16
        ln_split_kernel<<<M_TOK, 256, 0, stream>>>(tok, h_h, ln2_g + l * D_, ln2_b + l * D_);
        // weights -> blocked transposed fp16
        tconv_kernel<<<dim3(MLP_ / 32, D_ / 32), 256, 0, stream>>>(
            w1 + (long long)l * D_ * MLP_, w1t, D_, MLP_);
        tconv_kernel<<<dim3(D_ / 32, MLP_ / 32), 256, 0, stream>>>(
            w2 + (long long)l * MLP_ * D_, w2t, MLP_, D_);
        // MLP1: gelu(h @ w1 + b1) -> g blocked fp16
        launch_mfma(stream, h_h, w1t, b1 + (long long)l * MLP_,
                    nullptr, g_h, nullptr, M_TOK, MLP_, D_, M_TOK, MLP_, MLP_, M_TOK, 1, 0, 0, 1, 1,
                    Z0, Z0, Z0, Z0);
        // MLP2: tok += g @ w2 + b2  -- split-K x4: 1200 blocks, atomicAdd epilogue
        launch_mfma(stream, g_h, w2t, b2 + (long long)l * D_,
                    tok, nullptr, nullptr, M_TOK, D_, MLP_, M_TOK, D_, D_, 0, 0, 1, 0, 4, 4,
                    Z0, Z0, Z0, Z0);
    }

    // head: dedicated coalesced kernel (one thread per logit)
    head_kernel<<<dim3((OUT_ + 255) / 256, B_), 256, 0, stream>>>(tok, w_head, b_head, logits);
    head_softmax_kernel<<<B_, 256, 0, stream>>>(logits, out);
}